// Round 10
// baseline (136.509 us; speedup 1.0000x reference)
//
#include <hip/hip_runtime.h>
#include <math.h>

// Problem constants (fixed by reference)
#define H_DIM 256
#define NHEAD 8
#define DHEAD 32
#define NB 2
#define TSEQ 2048
#define LN_EPS 1e-5f

// softmax in exp2 domain: logit2 = s * (100/sqrt(32)) * log2(e).
// QK2_SCALE is folded into the packed Q fragments (proj frag-gen).
#define QK2_SCALE 25.503486f
#define SPLIT 4                         // key-split factor
#define TILES_PER (TSEQ / 64 / SPLIT)   // 8 k-tiles per block

typedef _Float16 half8 __attribute__((ext_vector_type(8)));
typedef _Float16 half4t __attribute__((ext_vector_type(4)));
typedef _Float16 half2t __attribute__((ext_vector_type(2)));
typedef float f32x4 __attribute__((ext_vector_type(4)));

__device__ __forceinline__ f32x4 mfma16(half8 a, half8 b, f32x4 c) {
  return __builtin_amdgcn_mfma_f32_16x16x32_f16(a, b, c, 0, 0, 0);
}
__device__ __forceinline__ float exp2fast(float x) {
  return __builtin_amdgcn_exp2f(x);
}
__device__ __forceinline__ half2t pkrtz(float a, float b) {
  return __builtin_bit_cast(half2t, __builtin_amdgcn_cvt_pkrtz(a, b));
}

// ---------------- masks: sign(sum|x|) per row ----------------
__global__ __launch_bounds__(256) void mask_kernel(
    const float* __restrict__ Q, const float* __restrict__ K,
    float* __restrict__ qmask, float* __restrict__ kmask) {
  const int wid = threadIdx.x >> 6, lane = threadIdx.x & 63;
  int row = blockIdx.x * 4 + wid;
  const int total_q = NB * TSEQ;
  const float* src;
  float* dst;
  if (row < total_q) { src = Q + (size_t)row * H_DIM; dst = qmask + row; }
  else               { src = K + (size_t)(row - total_q) * H_DIM; dst = kmask + (row - total_q); }
  float4 v = *(const float4*)(src + lane * 4);
  float s = fabsf(v.x) + fabsf(v.y) + fabsf(v.z) + fabsf(v.w);
  #pragma unroll
  for (int off = 32; off > 0; off >>= 1) s += __shfl_xor(s, off);
  if (lane == 0) *dst = (s != 0.0f) ? 1.0f : 0.0f;
}

// ---------------- W pre-pack (+ AmaskF build, blocks >= 96) ----------------
// W: fp32 -> hi/lo f16 B-fragment layout. AmaskF[n][tile][c][lane]: mask-row
// A-fragment (row0 = kmask as f16). Must launch AFTER mask_kernel.
__global__ __launch_bounds__(256) void prepack_kernel(
    const float* __restrict__ Wq, const float* __restrict__ Wk, const float* __restrict__ Wv,
    const float* __restrict__ kmask,
    half8* __restrict__ WpkHi, half8* __restrict__ WpkLo, half8* __restrict__ AmaskF) {
  if (blockIdx.x >= 96) {
    int slot2 = (blockIdx.x - 96) * 256 + threadIdx.x;   // 0..8191
    int n = slot2 >> 12;
    int rem = slot2 & 4095;
    int tile = rem >> 7;
    int c = (rem >> 6) & 1;
    int lane = rem & 63;
    int quad = lane >> 4, l15 = lane & 15;
    half8 am;
    #pragma unroll
    for (int j = 0; j < 8; ++j)
      am[j] = (l15 == 0) ? (_Float16)kmask[(size_t)n * TSEQ + tile * 64 + c * 32 + quad * 8 + j]
                         : (_Float16)0.0f;
    AmaskF[(((size_t)n * 32 + tile) * 2 + c) * 64 + lane] = am;
    return;
  }
  int slot = blockIdx.x * 256 + threadIdx.x;
  int lane = slot & 63;
  int fg = (slot >> 6) & 15;
  int s  = (slot >> 10) & 7;
  int which = slot >> 13;
  const float* W = which == 0 ? Wq : which == 1 ? Wk : Wv;
  int j  = fg * 16 + (lane & 15);
  int kb = s * 32 + (lane >> 4) * 8;
  half8 hi, lo;
  #pragma unroll
  for (int jj = 0; jj < 8; ++jj) {
    float x = W[(size_t)(kb + jj) * H_DIM + j];
    _Float16 h = (_Float16)x;
    hi[jj] = h;
    lo[jj] = (_Float16)(x - (float)h);
  }
  WpkHi[slot] = hi;
  WpkLo[slot] = lo;
}

// ---------------- fused projection + frag repack ----------------
// relu(X@W+b) via split-fp16 MFMA; result tile (64 t x 64 j = 2 heads) goes
// through LDS transpose and exits directly as MFMA fragment arrays:
//   Q/K: hi/lo split-f16 frags (Q pre-scaled by QK2_SCALE)
//   V:   transposed f16 frags, kmask- and t==2047-zeroed.
// No fp32 intermediate ever touches global memory.
__global__ __launch_bounds__(256) void proj_kernel(
    const float* __restrict__ Q, const float* __restrict__ K, const float* __restrict__ V,
    const float* __restrict__ bq, const float* __restrict__ bk, const float* __restrict__ bv,
    const half8* __restrict__ WpkHi, const half8* __restrict__ WpkLo,
    const float* __restrict__ kmask,
    half8* __restrict__ Gqhi, half8* __restrict__ Gqlo,
    half8* __restrict__ Gkhi, half8* __restrict__ Gklo, half8* __restrict__ Gv) {
  const int which = blockIdx.z;
  const float* X    = which == 0 ? Q  : which == 1 ? K  : V;
  const float* bias = which == 0 ? bq : which == 1 ? bk : bv;

  __shared__ __align__(16) float T[64 * 68];   // 17408 B, stride 68 words

  const int tid = threadIdx.x;
  const int w = tid >> 6, lane = tid & 63;
  const int l15 = lane & 15, quad = lane >> 4;
  const int mbase = blockIdx.y * 64;
  const int nfg   = blockIdx.x * 4;
  const int nn   = mbase >> 11;        // batch
  const int tile = blockIdx.y & 31;    // 64-row tile within batch

  half8 ahi[8], alo[8];
  {
    const float* xrow = X + (size_t)(mbase + w * 16 + l15) * H_DIM + quad * 8;
    #pragma unroll
    for (int s = 0; s < 8; ++s) {
      float4 a0 = *(const float4*)(xrow + s * 32);
      float4 a1 = *(const float4*)(xrow + s * 32 + 4);
      float xs[8] = {a0.x, a0.y, a0.z, a0.w, a1.x, a1.y, a1.z, a1.w};
      #pragma unroll
      for (int i = 0; i < 8; ++i) {
        _Float16 h = (_Float16)xs[i];
        ahi[s][i] = h;
        alo[s][i] = (_Float16)(xs[i] - (float)h);
      }
    }
  }

  f32x4 acc[4];
  #pragma unroll
  for (int f = 0; f < 4; ++f) acc[f] = (f32x4){0.f, 0.f, 0.f, 0.f};

  #pragma unroll
  for (int s = 0; s < 8; ++s) {
    const half8* ph = WpkHi + (((size_t)which * 8 + s) * 16 + nfg) * 64 + lane;
    const half8* pl = WpkLo + (((size_t)which * 8 + s) * 16 + nfg) * 64 + lane;
    #pragma unroll
    for (int f = 0; f < 4; ++f) {
      half8 BH = ph[f * 64];
      half8 BL = pl[f * 64];
      acc[f] = mfma16(ahi[s], BH, acc[f]);
      acc[f] = mfma16(ahi[s], BL, acc[f]);
      acc[f] = mfma16(alo[s], BH, acc[f]);
    }
  }

  // bias + relu (+ V last-key zero) -> LDS tile [t'][j]
  #pragma unroll
  for (int f = 0; f < 4; ++f) {
    float bj = bias[blockIdx.x * 64 + f * 16 + l15];
    #pragma unroll
    for (int r = 0; r < 4; ++r) {
      int row = w * 16 + quad * 4 + r;      // t' within tile
      float val = fmaxf(acc[f][r] + bj, 0.0f);
      if (which == 2 && ((mbase + row) & (TSEQ - 1)) == TSEQ - 1) val = 0.0f;
      T[row * 68 + f * 16 + l15] = val;
    }
  }
  __syncthreads();

  // fragment generation (2 heads per block: hs = 0,1 -> h = blockIdx.x*2+hs)
  if (which < 2) {
    const int fq = tid >> 6, lp = tid & 63;
    const int kdc = lp >> 4, krlo = lp & 15;
    const int row = fq * 16 + krlo;
    const float sc = (which == 0) ? QK2_SCALE : 1.0f;
    #pragma unroll
    for (int hs = 0; hs < 2; ++hs) {
      const float* p = &T[row * 68 + hs * 32 + kdc * 8];
      float4 a0 = *(const float4*)p;
      float4 a1 = *(const float4*)(p + 4);
      float xs[8] = {a0.x, a0.y, a0.z, a0.w, a1.x, a1.y, a1.z, a1.w};
      half8 hi, lo;
      #pragma unroll
      for (int i = 0; i < 8; ++i) {
        float x = xs[i] * sc;
        _Float16 h = (_Float16)x;
        hi[i] = h;
        lo[i] = (_Float16)(x - (float)h);
      }
      int hn = (blockIdx.x * 2 + hs) * NB + nn;
      size_t di = ((size_t)hn * 32 + tile) * 256 + tid;
      if (which == 0) { Gqhi[di] = hi; Gqlo[di] = lo; }
      else            { Gkhi[di] = hi; Gklo[di] = lo; }
    }
  } else {
    const int top = tid >> 6, mid = (tid >> 4) & 3, low = tid & 15;
    const int c = top >> 1, hh = top & 1;
    const int trow0 = (c * 4 + mid) * 8;
    float km[8];
    #pragma unroll
    for (int j = 0; j < 8; ++j)
      km[j] = kmask[(size_t)nn * TSEQ + tile * 64 + trow0 + j];
    #pragma unroll
    for (int hs = 0; hs < 2; ++hs) {
      const int col = hs * 32 + hh * 16 + low;
      half8 v8;
      #pragma unroll
      for (int j = 0; j < 8; ++j)
        v8[j] = (_Float16)(T[(trow0 + j) * 68 + col] * km[j]);
      int hn = (blockIdx.x * 2 + hs) * NB + nn;
      Gv[((size_t)hn * 32 + tile) * 256 + tid] = v8;
    }
  }
}

// ---------------- MFMA flash attention: barrier-free, transposed-S ----------------
// S^T = K·Q^T (rows=keys, cols=q). ALL operands (K, V, mask frags) are read
// directly from global (L2-hot, XCD-pinned working set <1 MB/XCD). The only
// LDS structure is the per-wave P round-trip -> ZERO __syncthreads: waves run
// free; latency hidden by 8 waves/SIMD instead of lock-step barriers.
__global__ __launch_bounds__(256) void attn_kernel(
    const half8* __restrict__ Gqhi, const half8* __restrict__ Gqlo,
    const half8* __restrict__ Gkhi, const half8* __restrict__ Gklo,
    const half8* __restrict__ Gv, const half8* __restrict__ AmaskF,
    _Float16* __restrict__ Opf, float* __restrict__ Mp, float* __restrict__ Lp) {
  __shared__ __align__(16) _Float16 Pbuf[4][16][72];    // per-wave only, 9216 B

  const int tid = threadIdx.x;
  const int w = tid >> 6, lane = tid & 63;
  const int l15 = lane & 15, quad = lane >> 4;

  const int b = blockIdx.x;
  const int g    = ((b & 7) << 1) | ((b >> 3) & 1);   // hn, XCD-pinned
  const int qt   = (b >> 4) & 31;
  const int sblk = b >> 9;                            // 0..3
  const int n = g & 1;

  const size_t fbase = (size_t)g * 32 * 256;
  const int tile0 = sblk * TILES_PER;

  // Q fragment (B-operand): col q = w*16 + l15, k(d) = quad*8..+8
  half8 qhi = Gqhi[fbase + (size_t)qt * 256 + w * 64 + lane];
  half8 qlo = Gqlo[fbase + (size_t)qt * 256 + w * 64 + lane];

  float m_q = -1.0e30f;
  f32x4 O0, O1, Ol;
  O0 = (f32x4){0.f, 0.f, 0.f, 0.f};
  O1 = (f32x4){0.f, 0.f, 0.f, 0.f};
  Ol = (f32x4){0.f, 0.f, 0.f, 0.f};

  const half8* kh  = Gkhi + fbase + (size_t)tile0 * 256 + lane;
  const half8* kl  = Gklo + fbase + (size_t)tile0 * 256 + lane;
  const half8* gv  = Gv   + fbase + (size_t)tile0 * 256 + lane;
  const half8* amp = AmaskF + (((size_t)n * 32 + tile0) * 2) * 64 + lane;

  #pragma unroll
  for (int tt = 0; tt < TILES_PER; ++tt) {
    // S^T = K Q^T (split-fp16): rows = keys f*16+quad*4+r, col = q = l15
    f32x4 S[4];
    #pragma unroll
    for (int f = 0; f < 4; ++f) {
      half8 KH = kh[f * 64];
      half8 KL = kl[f * 64];
      f32x4 a = (f32x4){0.f, 0.f, 0.f, 0.f};
      a = mfma16(KL, qhi, a);
      a = mfma16(KH, qlo, a);
      a = mfma16(KH, qhi, a);
      S[f] = a;
    }
    half8 am0 = amp[0];
    half8 am1 = amp[64];

    // per-q max: balanced tree + 2 shuffle stages
    float t0 = fmaxf(fmaxf(S[0][0], S[0][1]), fmaxf(S[0][2], S[0][3]));
    float t1 = fmaxf(fmaxf(S[1][0], S[1][1]), fmaxf(S[1][2], S[1][3]));
    float t2 = fmaxf(fmaxf(S[2][0], S[2][1]), fmaxf(S[2][2], S[2][3]));
    float t3 = fmaxf(fmaxf(S[3][0], S[3][1]), fmaxf(S[3][2], S[3][3]));
    float mx = fmaxf(fmaxf(t0, t1), fmaxf(t2, t3));
    mx = fmaxf(mx, __shfl_xor(mx, 16));
    mx = fmaxf(mx, __shfl_xor(mx, 32));

    float mnew = fmaxf(m_q, mx);
    float alpha = exp2fast(m_q - mnew);
    m_q = mnew;

    // P = exp2(S - m), pack pairs along keys -> Pbuf[q][key] (per-wave slice)
    #pragma unroll
    for (int f = 0; f < 4; ++f) {
      float p0 = exp2fast(S[f][0] - m_q);
      float p1 = exp2fast(S[f][1] - m_q);
      float p2 = exp2fast(S[f][2] - m_q);
      float p3 = exp2fast(S[f][3] - m_q);
      half2t a01 = pkrtz(p0, p1);
      half2t a23 = pkrtz(p2, p3);
      *(half2t*)&Pbuf[w][l15][f * 16 + quad * 4]     = a01;
      *(half2t*)&Pbuf[w][l15][f * 16 + quad * 4 + 2] = a23;
    }
    #pragma unroll
    for (int r = 0; r < 4; ++r) { O0[r] *= alpha; O1[r] *= alpha; }
    Ol[0] *= alpha;
    // in-wave LDS RAW: drain DS queue before reading P as B-fragments
    asm volatile("s_waitcnt lgkmcnt(0)" ::: "memory");

    // O += V^T P ; V/mask A-fragments straight from global (L2-hot)
    #pragma unroll
    for (int c = 0; c < 2; ++c) {
      half8 pb = *(const half8*)&Pbuf[w][l15][c * 32 + quad * 8];
      O0 = mfma16(gv[(c * 2 + 0) * 64], pb, O0);
      O1 = mfma16(gv[(c * 2 + 1) * 64], pb, O1);
      Ol = mfma16(c == 0 ? am0 : am1, pb, Ol);
    }

    kh += 256; kl += 256; gv += 256; amp += 128;
  }

  // epilogue: f16 partials (d = quad*4..+4 and +16), m/l from quad 0
  {
    int q = qt * 64 + w * 16 + l15;
    size_t idx = ((size_t)(sblk * 16 + g) * TSEQ + q) * DHEAD;
    half4t o0 = {(_Float16)O0[0], (_Float16)O0[1], (_Float16)O0[2], (_Float16)O0[3]};
    half4t o1 = {(_Float16)O1[0], (_Float16)O1[1], (_Float16)O1[2], (_Float16)O1[3]};
    *(half4t*)&Opf[idx + quad * 4]      = o0;
    *(half4t*)&Opf[idx + 16 + quad * 4] = o1;
    if (quad == 0) {
      Mp[(size_t)(sblk * 16 + g) * TSEQ + q] = m_q;
      Lp[(size_t)(sblk * 16 + g) * TSEQ + q] = Ol[0];
    }
  }
}

// ---------------- fused 4-way combine + layernorm + weight ----------------
__global__ __launch_bounds__(256) void ln_kernel(
    const _Float16* __restrict__ Opf, const float* __restrict__ Mp, const float* __restrict__ Lp,
    const float* __restrict__ gamma, const float* __restrict__ beta,
    const float* __restrict__ qmask,
    float* __restrict__ out, float* __restrict__ wout) {
  const int wid = threadIdx.x >> 6, lane = threadIdx.x & 63;
  const int row = blockIdx.x * 4 + wid;
  const int n = row >> 11, q = row & (TSEQ - 1);
  const int hh = lane >> 3;
  const int hn = hh * NB + n;
  const int dbase = (lane & 7) * 4;

  float m[SPLIT], l[SPLIT];
  half4t P[SPLIT];
  #pragma unroll
  for (int i = 0; i < SPLIT; ++i) {
    size_t si = (size_t)(i * 16 + hn) * TSEQ + q;
    P[i] = *(const half4t*)&Opf[si * DHEAD + dbase];
    m[i] = Mp[si];
    l[i] = Lp[si];
  }
  float mm = fmaxf(fmaxf(m[0], m[1]), fmaxf(m[2], m[3]));
  float denom = 0.f;
  float a[SPLIT];
  #pragma unroll
  for (int i = 0; i < SPLIT; ++i) { a[i] = exp2fast(m[i] - mm); denom += l[i] * a[i]; }
  float qm = qmask[row];
  float inv = qm / denom;

  float4 x = make_float4(0.f, 0.f, 0.f, 0.f);
  #pragma unroll
  for (int i = 0; i < SPLIT; ++i) {
    x.x += (float)P[i][0] * a[i]; x.y += (float)P[i][1] * a[i];
    x.z += (float)P[i][2] * a[i]; x.w += (float)P[i][3] * a[i];
  }
  x.x *= inv; x.y *= inv; x.z *= inv; x.w *= inv;

  float s = x.x + x.y + x.z + x.w;
  #pragma unroll
  for (int off = 32; off > 0; off >>= 1) s += __shfl_xor(s, off);
  float mu = s * (1.0f / H_DIM);
  float dx0 = x.x - mu, dx1 = x.y - mu, dx2 = x.z - mu, dx3 = x.w - mu;
  float sq = dx0 * dx0 + dx1 * dx1 + dx2 * dx2 + dx3 * dx3;
  #pragma unroll
  for (int off = 32; off > 0; off >>= 1) sq += __shfl_xor(sq, off);
  float rstd = rsqrtf(sq * (1.0f / H_DIM) + LN_EPS);
  float4 g = *(const float4*)(gamma + lane * 4);
  float4 bb = *(const float4*)(beta + lane * 4);
  float4 y;
  y.x = dx0 * rstd * g.x + bb.x;
  y.y = dx1 * rstd * g.y + bb.y;
  y.z = dx2 * rstd * g.z + bb.z;
  y.w = dx3 * rstd * g.w + bb.w;
  *(float4*)(out + (size_t)row * H_DIM + lane * 4) = y;
  if (lane == 0) wout[row] = qm * (1.0f / TSEQ);
}

extern "C" void kernel_launch(void* const* d_in, const int* in_sizes, int n_in,
                              void* d_out, int out_size, void* d_ws, size_t ws_size,
                              hipStream_t stream) {
  const float* Q  = (const float*)d_in[0];
  const float* K  = (const float*)d_in[1];
  const float* V  = (const float*)d_in[2];
  const float* Wq = (const float*)d_in[3];
  const float* bq = (const float*)d_in[4];
  const float* Wk = (const float*)d_in[5];
  const float* bk = (const float*)d_in[6];
  const float* Wv = (const float*)d_in[7];
  const float* bv = (const float*)d_in[8];
  const float* gamma = (const float*)d_in[9];
  const float* beta  = (const float*)d_in[10];

  char* ws = (char*)d_ws;
  const size_t NFRAG = (size_t)16 * 32 * 256;            // frags per array
  _Float16* Opf = (_Float16*)ws;                          // [SPLIT][16][TSEQ][32] f16 = 8 MB
  half8* Gqhi = (half8*)(ws + (size_t)SPLIT * 16 * TSEQ * DHEAD * 2);
  half8* Gqlo = Gqhi + NFRAG;
  half8* Gkhi = Gqlo + NFRAG;
  half8* Gklo = Gkhi + NFRAG;
  half8* Gv   = Gklo + NFRAG;
  float* Mp = (float*)(Gv + NFRAG);                       // [SPLIT][16][TSEQ]
  float* Lp = Mp + SPLIT * 16 * TSEQ;
  float* qmask = Lp + SPLIT * 16 * TSEQ;
  float* kmask = qmask + NB * TSEQ;
  half8* WpkHi = (half8*)(kmask + NB * TSEQ);
  half8* WpkLo = WpkHi + 24576;
  half8* AmaskF = WpkLo + 24576;                          // [NB][32][2][64]

  float* out  = (float*)d_out;
  float* wout = out + (size_t)NB * TSEQ * H_DIM;

  hipLaunchKernelGGL(mask_kernel, dim3(2 * NB * TSEQ / 4), dim3(256), 0, stream,
                     Q, K, qmask, kmask);
  hipLaunchKernelGGL(prepack_kernel, dim3(128), dim3(256), 0, stream,
                     Wq, Wk, Wv, kmask, WpkHi, WpkLo, AmaskF);
  hipLaunchKernelGGL(proj_kernel, dim3(H_DIM / 64, NB * TSEQ / 64, 3), dim3(256), 0, stream,
                     Q, K, V, bq, bk, bv, WpkHi, WpkLo, kmask,
                     Gqhi, Gqlo, Gkhi, Gklo, Gv);
  hipLaunchKernelGGL(attn_kernel, dim3(16 * 32 * SPLIT), dim3(256), 0, stream,
                     Gqhi, Gqlo, Gkhi, Gklo, Gv, AmaskF, Opf, Mp, Lp);
  hipLaunchKernelGGL(ln_kernel, dim3(NB * TSEQ / 4), dim3(256), 0, stream,
                     Opf, Mp, Lp, gamma, beta, qmask, out, wout);
}

// Round 11
// 134.808 us; speedup vs baseline: 1.0126x; 1.0126x over previous
//
#include <hip/hip_runtime.h>
#include <math.h>

// Problem constants (fixed by reference)
#define H_DIM 256
#define NHEAD 8
#define DHEAD 32
#define NB 2
#define TSEQ 2048
#define LN_EPS 1e-5f

// softmax in exp2 domain: logit2 = s * (100/sqrt(32)) * log2(e).
// QK2_SCALE is folded into the packed Q fragments (proj frag-gen).
#define QK2_SCALE 25.503486f
#define SPLIT 4                         // key-split factor
#define TILES_PER (TSEQ / 64 / SPLIT)   // 8 k-tiles per block

typedef _Float16 half8 __attribute__((ext_vector_type(8)));
typedef _Float16 half4t __attribute__((ext_vector_type(4)));
typedef _Float16 half2t __attribute__((ext_vector_type(2)));
typedef float f32x4 __attribute__((ext_vector_type(4)));

__device__ __forceinline__ f32x4 mfma16(half8 a, half8 b, f32x4 c) {
  return __builtin_amdgcn_mfma_f32_16x16x32_f16(a, b, c, 0, 0, 0);
}
__device__ __forceinline__ float exp2fast(float x) {
  return __builtin_amdgcn_exp2f(x);
}
__device__ __forceinline__ half2t pkrtz(float a, float b) {
  return __builtin_bit_cast(half2t, __builtin_amdgcn_cvt_pkrtz(a, b));
}

// ---------------- masks: sign(sum|x|) per row ----------------
__global__ __launch_bounds__(256) void mask_kernel(
    const float* __restrict__ Q, const float* __restrict__ K,
    float* __restrict__ qmask, float* __restrict__ kmask) {
  const int wid = threadIdx.x >> 6, lane = threadIdx.x & 63;
  int row = blockIdx.x * 4 + wid;
  const int total_q = NB * TSEQ;
  const float* src;
  float* dst;
  if (row < total_q) { src = Q + (size_t)row * H_DIM; dst = qmask + row; }
  else               { src = K + (size_t)(row - total_q) * H_DIM; dst = kmask + (row - total_q); }
  float4 v = *(const float4*)(src + lane * 4);
  float s = fabsf(v.x) + fabsf(v.y) + fabsf(v.z) + fabsf(v.w);
  #pragma unroll
  for (int off = 32; off > 0; off >>= 1) s += __shfl_xor(s, off);
  if (lane == 0) *dst = (s != 0.0f) ? 1.0f : 0.0f;
}

// ---------------- W pre-pack (+ AmaskF build, blocks >= 96) ----------------
// W: fp32 -> hi/lo f16 B-fragment layout. AmaskF[n][tile][c][lane]: mask-row
// A-fragment (row0 = kmask as f16). Must launch AFTER mask_kernel.
__global__ __launch_bounds__(256) void prepack_kernel(
    const float* __restrict__ Wq, const float* __restrict__ Wk, const float* __restrict__ Wv,
    const float* __restrict__ kmask,
    half8* __restrict__ WpkHi, half8* __restrict__ WpkLo, half8* __restrict__ AmaskF) {
  if (blockIdx.x >= 96) {
    int slot2 = (blockIdx.x - 96) * 256 + threadIdx.x;   // 0..8191
    int n = slot2 >> 12;
    int rem = slot2 & 4095;
    int tile = rem >> 7;
    int c = (rem >> 6) & 1;
    int lane = rem & 63;
    int quad = lane >> 4, l15 = lane & 15;
    half8 am;
    #pragma unroll
    for (int j = 0; j < 8; ++j)
      am[j] = (l15 == 0) ? (_Float16)kmask[(size_t)n * TSEQ + tile * 64 + c * 32 + quad * 8 + j]
                         : (_Float16)0.0f;
    AmaskF[(((size_t)n * 32 + tile) * 2 + c) * 64 + lane] = am;
    return;
  }
  int slot = blockIdx.x * 256 + threadIdx.x;
  int lane = slot & 63;
  int fg = (slot >> 6) & 15;
  int s  = (slot >> 10) & 7;
  int which = slot >> 13;
  const float* W = which == 0 ? Wq : which == 1 ? Wk : Wv;
  int j  = fg * 16 + (lane & 15);
  int kb = s * 32 + (lane >> 4) * 8;
  half8 hi, lo;
  #pragma unroll
  for (int jj = 0; jj < 8; ++jj) {
    float x = W[(size_t)(kb + jj) * H_DIM + j];
    _Float16 h = (_Float16)x;
    hi[jj] = h;
    lo[jj] = (_Float16)(x - (float)h);
  }
  WpkHi[slot] = hi;
  WpkLo[slot] = lo;
}

// ---------------- fused projection + frag repack ----------------
// relu(X@W+b) via split-fp16 MFMA; result tile (64 t x 64 j = 2 heads) goes
// through LDS transpose and exits directly as MFMA fragment arrays:
//   Q/K: hi/lo split-f16 frags (Q pre-scaled by QK2_SCALE)
//   V:   transposed f16 frags, kmask- and t==2047-zeroed.
// No fp32 intermediate ever touches global memory.
__global__ __launch_bounds__(256) void proj_kernel(
    const float* __restrict__ Q, const float* __restrict__ K, const float* __restrict__ V,
    const float* __restrict__ bq, const float* __restrict__ bk, const float* __restrict__ bv,
    const half8* __restrict__ WpkHi, const half8* __restrict__ WpkLo,
    const float* __restrict__ kmask,
    half8* __restrict__ Gqhi, half8* __restrict__ Gqlo,
    half8* __restrict__ Gkhi, half8* __restrict__ Gklo, half8* __restrict__ Gv) {
  const int which = blockIdx.z;
  const float* X    = which == 0 ? Q  : which == 1 ? K  : V;
  const float* bias = which == 0 ? bq : which == 1 ? bk : bv;

  __shared__ __align__(16) float T[64 * 68];   // 17408 B, stride 68 words

  const int tid = threadIdx.x;
  const int w = tid >> 6, lane = tid & 63;
  const int l15 = lane & 15, quad = lane >> 4;
  const int mbase = blockIdx.y * 64;
  const int nfg   = blockIdx.x * 4;
  const int nn   = mbase >> 11;        // batch
  const int tile = blockIdx.y & 31;    // 64-row tile within batch

  half8 ahi[8], alo[8];
  {
    const float* xrow = X + (size_t)(mbase + w * 16 + l15) * H_DIM + quad * 8;
    #pragma unroll
    for (int s = 0; s < 8; ++s) {
      float4 a0 = *(const float4*)(xrow + s * 32);
      float4 a1 = *(const float4*)(xrow + s * 32 + 4);
      float xs[8] = {a0.x, a0.y, a0.z, a0.w, a1.x, a1.y, a1.z, a1.w};
      #pragma unroll
      for (int i = 0; i < 8; ++i) {
        _Float16 h = (_Float16)xs[i];
        ahi[s][i] = h;
        alo[s][i] = (_Float16)(xs[i] - (float)h);
      }
    }
  }

  f32x4 acc[4];
  #pragma unroll
  for (int f = 0; f < 4; ++f) acc[f] = (f32x4){0.f, 0.f, 0.f, 0.f};

  #pragma unroll
  for (int s = 0; s < 8; ++s) {
    const half8* ph = WpkHi + (((size_t)which * 8 + s) * 16 + nfg) * 64 + lane;
    const half8* pl = WpkLo + (((size_t)which * 8 + s) * 16 + nfg) * 64 + lane;
    #pragma unroll
    for (int f = 0; f < 4; ++f) {
      half8 BH = ph[f * 64];
      half8 BL = pl[f * 64];
      acc[f] = mfma16(ahi[s], BH, acc[f]);
      acc[f] = mfma16(ahi[s], BL, acc[f]);
      acc[f] = mfma16(alo[s], BH, acc[f]);
    }
  }

  // bias + relu (+ V last-key zero) -> LDS tile [t'][j]
  #pragma unroll
  for (int f = 0; f < 4; ++f) {
    float bj = bias[blockIdx.x * 64 + f * 16 + l15];
    #pragma unroll
    for (int r = 0; r < 4; ++r) {
      int row = w * 16 + quad * 4 + r;      // t' within tile
      float val = fmaxf(acc[f][r] + bj, 0.0f);
      if (which == 2 && ((mbase + row) & (TSEQ - 1)) == TSEQ - 1) val = 0.0f;
      T[row * 68 + f * 16 + l15] = val;
    }
  }
  __syncthreads();

  // fragment generation (2 heads per block: hs = 0,1 -> h = blockIdx.x*2+hs)
  if (which < 2) {
    const int fq = tid >> 6, lp = tid & 63;
    const int kdc = lp >> 4, krlo = lp & 15;
    const int row = fq * 16 + krlo;
    const float sc = (which == 0) ? QK2_SCALE : 1.0f;
    #pragma unroll
    for (int hs = 0; hs < 2; ++hs) {
      const float* p = &T[row * 68 + hs * 32 + kdc * 8];
      float4 a0 = *(const float4*)p;
      float4 a1 = *(const float4*)(p + 4);
      float xs[8] = {a0.x, a0.y, a0.z, a0.w, a1.x, a1.y, a1.z, a1.w};
      half8 hi, lo;
      #pragma unroll
      for (int i = 0; i < 8; ++i) {
        float x = xs[i] * sc;
        _Float16 h = (_Float16)x;
        hi[i] = h;
        lo[i] = (_Float16)(x - (float)h);
      }
      int hn = (blockIdx.x * 2 + hs) * NB + nn;
      size_t di = ((size_t)hn * 32 + tile) * 256 + tid;
      if (which == 0) { Gqhi[di] = hi; Gqlo[di] = lo; }
      else            { Gkhi[di] = hi; Gklo[di] = lo; }
    }
  } else {
    const int top = tid >> 6, mid = (tid >> 4) & 3, low = tid & 15;
    const int c = top >> 1, hh = top & 1;
    const int trow0 = (c * 4 + mid) * 8;
    float km[8];
    #pragma unroll
    for (int j = 0; j < 8; ++j)
      km[j] = kmask[(size_t)nn * TSEQ + tile * 64 + trow0 + j];
    #pragma unroll
    for (int hs = 0; hs < 2; ++hs) {
      const int col = hs * 32 + hh * 16 + low;
      half8 v8;
      #pragma unroll
      for (int j = 0; j < 8; ++j)
        v8[j] = (_Float16)(T[(trow0 + j) * 68 + col] * km[j]);
      int hn = (blockIdx.x * 2 + hs) * NB + nn;
      Gv[((size_t)hn * 32 + tile) * 256 + tid] = v8;
    }
  }
}

// ---------------- MFMA flash attention: wide waves (32 q/wave), key-split x4 ----------------
// S^T = K·Q^T. Block = 128 q (2 q-groups per wave): each K/am fragment load
// feeds TWO QK MFMA groups -> K/am L2 traffic halved vs 16 q/wave. V staged
// once per block in LDS (double-buffered, one barrier/tile). Grid 1024 =
// 4 blocks/CU, fully resident.
__global__ __launch_bounds__(256) void attn_kernel(
    const half8* __restrict__ Gqhi, const half8* __restrict__ Gqlo,
    const half8* __restrict__ Gkhi, const half8* __restrict__ Gklo,
    const half8* __restrict__ Gv, const half8* __restrict__ AmaskF,
    _Float16* __restrict__ Opf, float* __restrict__ Mp, float* __restrict__ Lp) {
  __shared__ __align__(16) half8 Vf[2][256];            // 8 KB double-buffered
  __shared__ __align__(16) _Float16 Pbuf[4][32][72];    // [wave][q(2 groups)][key]

  const int tid = threadIdx.x;
  const int w = tid >> 6, lane = tid & 63;
  const int l15 = lane & 15, quad = lane >> 4;

  const int b = blockIdx.x;
  const int g    = ((b & 7) << 1) | ((b >> 3) & 1);   // hn, XCD-pinned
  const int qt   = (b >> 4) & 15;                     // 128-q tile
  const int sblk = b >> 8;                            // 0..3
  const int n = g & 1;

  const size_t fbase = (size_t)g * 32 * 256;
  const int tile0 = sblk * TILES_PER;

  // Q fragments (B-operand) for both q-groups: q0 = qt*128 + w*16 + l15, q1 = q0 + 64
  half8 qhi0 = Gqhi[fbase + (size_t)(qt * 2 + 0) * 256 + w * 64 + lane];
  half8 qlo0 = Gqlo[fbase + (size_t)(qt * 2 + 0) * 256 + w * 64 + lane];
  half8 qhi1 = Gqhi[fbase + (size_t)(qt * 2 + 1) * 256 + w * 64 + lane];
  half8 qlo1 = Gqlo[fbase + (size_t)(qt * 2 + 1) * 256 + w * 64 + lane];

  float m_q0 = -1.0e30f, m_q1 = -1.0e30f;
  f32x4 O00, O01, Ol0, O10, O11, Ol1;
  O00 = O01 = Ol0 = O10 = O11 = Ol1 = (f32x4){0.f, 0.f, 0.f, 0.f};

  const half8* kh  = Gkhi + fbase + (size_t)tile0 * 256 + lane;
  const half8* kl  = Gklo + fbase + (size_t)tile0 * 256 + lane;
  const half8* gv  = Gv   + fbase + (size_t)tile0 * 256 + tid;
  const half8* amp = AmaskF + (((size_t)n * 32 + tile0) * 2) * 64 + lane;

  Vf[0][tid] = gv[0];

  #pragma unroll
  for (int tt = 0; tt < TILES_PER; ++tt) {
    half8 vnext;
    if (tt < TILES_PER - 1) vnext = gv[256];
    half8 am0 = amp[0];
    half8 am1 = amp[64];

    __syncthreads();     // Vf[tt&1] writes visible; all reads of Vf[(tt+1)&1] done
    if (tt < TILES_PER - 1)
      Vf[(tt + 1) & 1][tid] = vnext;

    // S^T = K Q^T (split-fp16); each K frag load feeds BOTH q-groups
    f32x4 S0[4], S1[4];
    #pragma unroll
    for (int f = 0; f < 4; ++f) {
      half8 KH = kh[f * 64];
      half8 KL = kl[f * 64];
      f32x4 a0 = (f32x4){0.f, 0.f, 0.f, 0.f};
      a0 = mfma16(KL, qhi0, a0);
      a0 = mfma16(KH, qlo0, a0);
      a0 = mfma16(KH, qhi0, a0);
      S0[f] = a0;
      f32x4 a1 = (f32x4){0.f, 0.f, 0.f, 0.f};
      a1 = mfma16(KL, qhi1, a1);
      a1 = mfma16(KH, qlo1, a1);
      a1 = mfma16(KH, qhi1, a1);
      S1[f] = a1;
    }

    // per-q max + online softmax, q-group 0
    {
      float t0 = fmaxf(fmaxf(S0[0][0], S0[0][1]), fmaxf(S0[0][2], S0[0][3]));
      float t1 = fmaxf(fmaxf(S0[1][0], S0[1][1]), fmaxf(S0[1][2], S0[1][3]));
      float t2 = fmaxf(fmaxf(S0[2][0], S0[2][1]), fmaxf(S0[2][2], S0[2][3]));
      float t3 = fmaxf(fmaxf(S0[3][0], S0[3][1]), fmaxf(S0[3][2], S0[3][3]));
      float mx = fmaxf(fmaxf(t0, t1), fmaxf(t2, t3));
      mx = fmaxf(mx, __shfl_xor(mx, 16));
      mx = fmaxf(mx, __shfl_xor(mx, 32));
      float mnew = fmaxf(m_q0, mx);
      float alpha = exp2fast(m_q0 - mnew);
      m_q0 = mnew;
      #pragma unroll
      for (int f = 0; f < 4; ++f) {
        float p0 = exp2fast(S0[f][0] - m_q0);
        float p1 = exp2fast(S0[f][1] - m_q0);
        float p2 = exp2fast(S0[f][2] - m_q0);
        float p3 = exp2fast(S0[f][3] - m_q0);
        *(half2t*)&Pbuf[w][l15][f * 16 + quad * 4]     = pkrtz(p0, p1);
        *(half2t*)&Pbuf[w][l15][f * 16 + quad * 4 + 2] = pkrtz(p2, p3);
      }
      #pragma unroll
      for (int r = 0; r < 4; ++r) { O00[r] *= alpha; O01[r] *= alpha; }
      Ol0[0] *= alpha;
    }
    // q-group 1
    {
      float t0 = fmaxf(fmaxf(S1[0][0], S1[0][1]), fmaxf(S1[0][2], S1[0][3]));
      float t1 = fmaxf(fmaxf(S1[1][0], S1[1][1]), fmaxf(S1[1][2], S1[1][3]));
      float t2 = fmaxf(fmaxf(S1[2][0], S1[2][1]), fmaxf(S1[2][2], S1[2][3]));
      float t3 = fmaxf(fmaxf(S1[3][0], S1[3][1]), fmaxf(S1[3][2], S1[3][3]));
      float mx = fmaxf(fmaxf(t0, t1), fmaxf(t2, t3));
      mx = fmaxf(mx, __shfl_xor(mx, 16));
      mx = fmaxf(mx, __shfl_xor(mx, 32));
      float mnew = fmaxf(m_q1, mx);
      float alpha = exp2fast(m_q1 - mnew);
      m_q1 = mnew;
      #pragma unroll
      for (int f = 0; f < 4; ++f) {
        float p0 = exp2fast(S1[f][0] - m_q1);
        float p1 = exp2fast(S1[f][1] - m_q1);
        float p2 = exp2fast(S1[f][2] - m_q1);
        float p3 = exp2fast(S1[f][3] - m_q1);
        *(half2t*)&Pbuf[w][16 + l15][f * 16 + quad * 4]     = pkrtz(p0, p1);
        *(half2t*)&Pbuf[w][16 + l15][f * 16 + quad * 4 + 2] = pkrtz(p2, p3);
      }
      #pragma unroll
      for (int r = 0; r < 4; ++r) { O10[r] *= alpha; O11[r] *= alpha; }
      Ol1[0] *= alpha;
    }
    // in-wave LDS RAW: drain DS queue before reading P as B-fragments
    asm volatile("s_waitcnt lgkmcnt(0)" ::: "memory");

    // O += V^T P ; V frags from LDS reused across both q-groups
    const half8* vbuf = (const half8*)Vf[tt & 1];
    #pragma unroll
    for (int c = 0; c < 2; ++c) {
      half8 vA = vbuf[(c * 2 + 0) * 64 + lane];
      half8 vB = vbuf[(c * 2 + 1) * 64 + lane];
      half8 amc = (c == 0) ? am0 : am1;
      half8 pb0 = *(const half8*)&Pbuf[w][l15][c * 32 + quad * 8];
      half8 pb1 = *(const half8*)&Pbuf[w][16 + l15][c * 32 + quad * 8];
      O00 = mfma16(vA, pb0, O00);
      O01 = mfma16(vB, pb0, O01);
      Ol0 = mfma16(amc, pb0, Ol0);
      O10 = mfma16(vA, pb1, O10);
      O11 = mfma16(vB, pb1, O11);
      Ol1 = mfma16(amc, pb1, Ol1);
    }

    kh += 256; kl += 256; gv += 256; amp += 128;
  }

  // epilogue: f16 partials for both q-groups, m/l from quad 0
  {
    int q0 = qt * 128 + w * 16 + l15;
    size_t base = (size_t)(sblk * 16 + g) * TSEQ;
    size_t i0 = (base + q0) * DHEAD;
    size_t i1 = (base + q0 + 64) * DHEAD;
    half4t a0 = {(_Float16)O00[0], (_Float16)O00[1], (_Float16)O00[2], (_Float16)O00[3]};
    half4t a1 = {(_Float16)O01[0], (_Float16)O01[1], (_Float16)O01[2], (_Float16)O01[3]};
    half4t b0 = {(_Float16)O10[0], (_Float16)O10[1], (_Float16)O10[2], (_Float16)O10[3]};
    half4t b1 = {(_Float16)O11[0], (_Float16)O11[1], (_Float16)O11[2], (_Float16)O11[3]};
    *(half4t*)&Opf[i0 + quad * 4]      = a0;
    *(half4t*)&Opf[i0 + 16 + quad * 4] = a1;
    *(half4t*)&Opf[i1 + quad * 4]      = b0;
    *(half4t*)&Opf[i1 + 16 + quad * 4] = b1;
    if (quad == 0) {
      Mp[base + q0]      = m_q0;
      Lp[base + q0]      = Ol0[0];
      Mp[base + q0 + 64] = m_q1;
      Lp[base + q0 + 64] = Ol1[0];
    }
  }
}

// ---------------- fused 4-way combine + layernorm + weight ----------------
__global__ __launch_bounds__(256) void ln_kernel(
    const _Float16* __restrict__ Opf, const float* __restrict__ Mp, const float* __restrict__ Lp,
    const float* __restrict__ gamma, const float* __restrict__ beta,
    const float* __restrict__ qmask,
    float* __restrict__ out, float* __restrict__ wout) {
  const int wid = threadIdx.x >> 6, lane = threadIdx.x & 63;
  const int row = blockIdx.x * 4 + wid;
  const int n = row >> 11, q = row & (TSEQ - 1);
  const int hh = lane >> 3;
  const int hn = hh * NB + n;
  const int dbase = (lane & 7) * 4;

  float m[SPLIT], l[SPLIT];
  half4t P[SPLIT];
  #pragma unroll
  for (int i = 0; i < SPLIT; ++i) {
    size_t si = (size_t)(i * 16 + hn) * TSEQ + q;
    P[i] = *(const half4t*)&Opf[si * DHEAD + dbase];
    m[i] = Mp[si];
    l[i] = Lp[si];
  }
  float mm = fmaxf(fmaxf(m[0], m[1]), fmaxf(m[2], m[3]));
  float denom = 0.f;
  float a[SPLIT];
  #pragma unroll
  for (int i = 0; i < SPLIT; ++i) { a[i] = exp2fast(m[i] - mm); denom += l[i] * a[i]; }
  float qm = qmask[row];
  float inv = qm / denom;

  float4 x = make_float4(0.f, 0.f, 0.f, 0.f);
  #pragma unroll
  for (int i = 0; i < SPLIT; ++i) {
    x.x += (float)P[i][0] * a[i]; x.y += (float)P[i][1] * a[i];
    x.z += (float)P[i][2] * a[i]; x.w += (float)P[i][3] * a[i];
  }
  x.x *= inv; x.y *= inv; x.z *= inv; x.w *= inv;

  float s = x.x + x.y + x.z + x.w;
  #pragma unroll
  for (int off = 32; off > 0; off >>= 1) s += __shfl_xor(s, off);
  float mu = s * (1.0f / H_DIM);
  float dx0 = x.x - mu, dx1 = x.y - mu, dx2 = x.z - mu, dx3 = x.w - mu;
  float sq = dx0 * dx0 + dx1 * dx1 + dx2 * dx2 + dx3 * dx3;
  #pragma unroll
  for (int off = 32; off > 0; off >>= 1) sq += __shfl_xor(sq, off);
  float rstd = rsqrtf(sq * (1.0f / H_DIM) + LN_EPS);
  float4 g = *(const float4*)(gamma + lane * 4);
  float4 bb = *(const float4*)(beta + lane * 4);
  float4 y;
  y.x = dx0 * rstd * g.x + bb.x;
  y.y = dx1 * rstd * g.y + bb.y;
  y.z = dx2 * rstd * g.z + bb.z;
  y.w = dx3 * rstd * g.w + bb.w;
  *(float4*)(out + (size_t)row * H_DIM + lane * 4) = y;
  if (lane == 0) wout[row] = qm * (1.0f / TSEQ);
}

extern "C" void kernel_launch(void* const* d_in, const int* in_sizes, int n_in,
                              void* d_out, int out_size, void* d_ws, size_t ws_size,
                              hipStream_t stream) {
  const float* Q  = (const float*)d_in[0];
  const float* K  = (const float*)d_in[1];
  const float* V  = (const float*)d_in[2];
  const float* Wq = (const float*)d_in[3];
  const float* bq = (const float*)d_in[4];
  const float* Wk = (const float*)d_in[5];
  const float* bk = (const float*)d_in[6];
  const float* Wv = (const float*)d_in[7];
  const float* bv = (const float*)d_in[8];
  const float* gamma = (const float*)d_in[9];
  const float* beta  = (const float*)d_in[10];

  char* ws = (char*)d_ws;
  const size_t NFRAG = (size_t)16 * 32 * 256;            // frags per array
  _Float16* Opf = (_Float16*)ws;                          // [SPLIT][16][TSEQ][32] f16 = 8 MB
  half8* Gqhi = (half8*)(ws + (size_t)SPLIT * 16 * TSEQ * DHEAD * 2);
  half8* Gqlo = Gqhi + NFRAG;
  half8* Gkhi = Gqlo + NFRAG;
  half8* Gklo = Gkhi + NFRAG;
  half8* Gv   = Gklo + NFRAG;
  float* Mp = (float*)(Gv + NFRAG);                       // [SPLIT][16][TSEQ]
  float* Lp = Mp + SPLIT * 16 * TSEQ;
  float* qmask = Lp + SPLIT * 16 * TSEQ;
  float* kmask = qmask + NB * TSEQ;
  half8* WpkHi = (half8*)(kmask + NB * TSEQ);
  half8* WpkLo = WpkHi + 24576;
  half8* AmaskF = WpkLo + 24576;                          // [NB][32][2][64]

  float* out  = (float*)d_out;
  float* wout = out + (size_t)NB * TSEQ * H_DIM;

  hipLaunchKernelGGL(mask_kernel, dim3(2 * NB * TSEQ / 4), dim3(256), 0, stream,
                     Q, K, qmask, kmask);
  hipLaunchKernelGGL(prepack_kernel, dim3(128), dim3(256), 0, stream,
                     Wq, Wk, Wv, kmask, WpkHi, WpkLo, AmaskF);
  hipLaunchKernelGGL(proj_kernel, dim3(H_DIM / 64, NB * TSEQ / 64, 3), dim3(256), 0, stream,
                     Q, K, V, bq, bk, bv, WpkHi, WpkLo, kmask,
                     Gqhi, Gqlo, Gkhi, Gklo, Gv);
  hipLaunchKernelGGL(attn_kernel, dim3(16 * 16 * SPLIT), dim3(256), 0, stream,
                     Gqhi, Gqlo, Gkhi, Gklo, Gv, AmaskF, Opf, Mp, Lp);
  hipLaunchKernelGGL(ln_kernel, dim3(NB * TSEQ / 4), dim3(256), 0, stream,
                     Opf, Mp, Lp, gamma, beta, qmask, out, wout);
}

// Round 12
// 131.895 us; speedup vs baseline: 1.0350x; 1.0221x over previous
//
#include <hip/hip_runtime.h>
#include <math.h>

// Problem constants (fixed by reference)
#define H_DIM 256
#define NHEAD 8
#define DHEAD 32
#define NB 2
#define TSEQ 2048
#define LN_EPS 1e-5f

// softmax in exp2 domain: logit2 = s * (100/sqrt(32)) * log2(e).
// QK2_SCALE is folded into the packed Q fragments (proj frag-gen).
#define QK2_SCALE 25.503486f
#define SPLIT 4                         // key-split factor
#define TILES_PER (TSEQ / 64 / SPLIT)   // 8 k-tiles per block

typedef _Float16 half8 __attribute__((ext_vector_type(8)));
typedef _Float16 half4t __attribute__((ext_vector_type(4)));
typedef _Float16 half2t __attribute__((ext_vector_type(2)));
typedef float f32x4 __attribute__((ext_vector_type(4)));

__device__ __forceinline__ f32x4 mfma16(half8 a, half8 b, f32x4 c) {
  return __builtin_amdgcn_mfma_f32_16x16x32_f16(a, b, c, 0, 0, 0);
}
__device__ __forceinline__ float exp2fast(float x) {
  return __builtin_amdgcn_exp2f(x);
}
__device__ __forceinline__ half2t pkrtz(float a, float b) {
  return __builtin_bit_cast(half2t, __builtin_amdgcn_cvt_pkrtz(a, b));
}

// ---------------- W pre-pack + kmask (blocks >= 96) ----------------
// Blocks 0..95: W fp32 -> hi/lo f16 B-fragment layout.
// Blocks 96..1119: kmask[n][t] = sign(sum|K_raw row|), one wave per row.
__global__ __launch_bounds__(256) void prepack_kernel(
    const float* __restrict__ Wq, const float* __restrict__ Wk, const float* __restrict__ Wv,
    const float* __restrict__ Kraw,
    half8* __restrict__ WpkHi, half8* __restrict__ WpkLo, float* __restrict__ kmask) {
  if (blockIdx.x >= 96) {
    const int wid = threadIdx.x >> 6, lane = threadIdx.x & 63;
    int row = (blockIdx.x - 96) * 4 + wid;              // 0..NB*TSEQ-1
    float4 v = *(const float4*)(Kraw + (size_t)row * H_DIM + lane * 4);
    float s = fabsf(v.x) + fabsf(v.y) + fabsf(v.z) + fabsf(v.w);
    #pragma unroll
    for (int off = 32; off > 0; off >>= 1) s += __shfl_xor(s, off);
    if (lane == 0) kmask[row] = (s != 0.0f) ? 1.0f : 0.0f;
    return;
  }
  int slot = blockIdx.x * 256 + threadIdx.x;
  int lane = slot & 63;
  int fg = (slot >> 6) & 15;
  int s  = (slot >> 10) & 7;
  int which = slot >> 13;
  const float* W = which == 0 ? Wq : which == 1 ? Wk : Wv;
  int j  = fg * 16 + (lane & 15);
  int kb = s * 32 + (lane >> 4) * 8;
  half8 hi, lo;
  #pragma unroll
  for (int jj = 0; jj < 8; ++jj) {
    float x = W[(size_t)(kb + jj) * H_DIM + j];
    _Float16 h = (_Float16)x;
    hi[jj] = h;
    lo[jj] = (_Float16)(x - (float)h);
  }
  WpkHi[slot] = hi;
  WpkLo[slot] = lo;
}

// ---------------- fused projection + frag repack ----------------
// relu(X@W+b) via split-fp16 MFMA; result tile (64 t x 64 j = 2 heads) goes
// through LDS transpose and exits directly as MFMA fragment arrays:
//   Q/K: hi/lo split-f16 frags (Q pre-scaled by QK2_SCALE)
//   V:   transposed f16 frags, t==2047 zeroed (reference drops last key in PV).
// Key masking is applied to P inside attn (register multiply) — no V pre-mask.
__global__ __launch_bounds__(256) void proj_kernel(
    const float* __restrict__ Q, const float* __restrict__ K, const float* __restrict__ V,
    const float* __restrict__ bq, const float* __restrict__ bk, const float* __restrict__ bv,
    const half8* __restrict__ WpkHi, const half8* __restrict__ WpkLo,
    half8* __restrict__ Gqhi, half8* __restrict__ Gqlo,
    half8* __restrict__ Gkhi, half8* __restrict__ Gklo, half8* __restrict__ Gv) {
  const int which = blockIdx.z;
  const float* X    = which == 0 ? Q  : which == 1 ? K  : V;
  const float* bias = which == 0 ? bq : which == 1 ? bk : bv;

  __shared__ __align__(16) float T[64 * 68];   // 17408 B, stride 68 words

  const int tid = threadIdx.x;
  const int w = tid >> 6, lane = tid & 63;
  const int l15 = lane & 15, quad = lane >> 4;
  const int mbase = blockIdx.y * 64;
  const int nfg   = blockIdx.x * 4;
  const int nn   = mbase >> 11;        // batch
  const int tile = blockIdx.y & 31;    // 64-row tile within batch

  half8 ahi[8], alo[8];
  {
    const float* xrow = X + (size_t)(mbase + w * 16 + l15) * H_DIM + quad * 8;
    #pragma unroll
    for (int s = 0; s < 8; ++s) {
      float4 a0 = *(const float4*)(xrow + s * 32);
      float4 a1 = *(const float4*)(xrow + s * 32 + 4);
      float xs[8] = {a0.x, a0.y, a0.z, a0.w, a1.x, a1.y, a1.z, a1.w};
      #pragma unroll
      for (int i = 0; i < 8; ++i) {
        _Float16 h = (_Float16)xs[i];
        ahi[s][i] = h;
        alo[s][i] = (_Float16)(xs[i] - (float)h);
      }
    }
  }

  f32x4 acc[4];
  #pragma unroll
  for (int f = 0; f < 4; ++f) acc[f] = (f32x4){0.f, 0.f, 0.f, 0.f};

  #pragma unroll
  for (int s = 0; s < 8; ++s) {
    const half8* ph = WpkHi + (((size_t)which * 8 + s) * 16 + nfg) * 64 + lane;
    const half8* pl = WpkLo + (((size_t)which * 8 + s) * 16 + nfg) * 64 + lane;
    #pragma unroll
    for (int f = 0; f < 4; ++f) {
      half8 BH = ph[f * 64];
      half8 BL = pl[f * 64];
      acc[f] = mfma16(ahi[s], BH, acc[f]);
      acc[f] = mfma16(ahi[s], BL, acc[f]);
      acc[f] = mfma16(alo[s], BH, acc[f]);
    }
  }

  // bias + relu (+ V last-key zero) -> LDS tile [t'][j]
  #pragma unroll
  for (int f = 0; f < 4; ++f) {
    float bj = bias[blockIdx.x * 64 + f * 16 + l15];
    #pragma unroll
    for (int r = 0; r < 4; ++r) {
      int row = w * 16 + quad * 4 + r;      // t' within tile
      float val = fmaxf(acc[f][r] + bj, 0.0f);
      if (which == 2 && ((mbase + row) & (TSEQ - 1)) == TSEQ - 1) val = 0.0f;
      T[row * 68 + f * 16 + l15] = val;
    }
  }
  __syncthreads();

  // fragment generation (2 heads per block: hs = 0,1 -> h = blockIdx.x*2+hs)
  if (which < 2) {
    const int fq = tid >> 6, lp = tid & 63;
    const int kdc = lp >> 4, krlo = lp & 15;
    const int row = fq * 16 + krlo;
    const float sc = (which == 0) ? QK2_SCALE : 1.0f;
    #pragma unroll
    for (int hs = 0; hs < 2; ++hs) {
      const float* p = &T[row * 68 + hs * 32 + kdc * 8];
      float4 a0 = *(const float4*)p;
      float4 a1 = *(const float4*)(p + 4);
      float xs[8] = {a0.x, a0.y, a0.z, a0.w, a1.x, a1.y, a1.z, a1.w};
      half8 hi, lo;
      #pragma unroll
      for (int i = 0; i < 8; ++i) {
        float x = xs[i] * sc;
        _Float16 h = (_Float16)x;
        hi[i] = h;
        lo[i] = (_Float16)(x - (float)h);
      }
      int hn = (blockIdx.x * 2 + hs) * NB + nn;
      size_t di = ((size_t)hn * 32 + tile) * 256 + tid;
      if (which == 0) { Gqhi[di] = hi; Gqlo[di] = lo; }
      else            { Gkhi[di] = hi; Gklo[di] = lo; }
    }
  } else {
    const int top = tid >> 6, mid = (tid >> 4) & 3, low = tid & 15;
    const int c = top >> 1, hh = top & 1;
    const int trow0 = (c * 4 + mid) * 8;
    #pragma unroll
    for (int hs = 0; hs < 2; ++hs) {
      const int col = hs * 32 + hh * 16 + low;
      half8 v8;
      #pragma unroll
      for (int j = 0; j < 8; ++j)
        v8[j] = (_Float16)T[(trow0 + j) * 68 + col];
      int hn = (blockIdx.x * 2 + hs) * NB + nn;
      Gv[((size_t)hn * 32 + tile) * 256 + tid] = v8;
    }
  }
}

// ---------------- MFMA flash attention (R9 core), key-split x4 ----------------
// S^T = K·Q^T (rows=keys, cols=q); K fragments pipelined global->reg; V
// double-buffered in LDS (one barrier/tile); P masked by kmask IN REGISTERS;
// l-row via compile-time ones A-frag MFMA; f16 partial output.
__global__ __launch_bounds__(256) void attn_kernel(
    const half8* __restrict__ Gqhi, const half8* __restrict__ Gqlo,
    const half8* __restrict__ Gkhi, const half8* __restrict__ Gklo,
    const half8* __restrict__ Gv, const float* __restrict__ kmask,
    _Float16* __restrict__ Opf, float* __restrict__ Mp, float* __restrict__ Lp) {
  __shared__ __align__(16) half8 Vf[2][256];            // 8 KB double-buffered
  __shared__ __align__(16) _Float16 Pbuf[4][16][72];    // [wave][q][key], stride 144B

  const int tid = threadIdx.x;
  const int w = tid >> 6, lane = tid & 63;
  const int l15 = lane & 15, quad = lane >> 4;

  const int b = blockIdx.x;
  const int g    = ((b & 7) << 1) | ((b >> 3) & 1);   // hn, XCD-pinned
  const int qt   = (b >> 4) & 31;
  const int sblk = b >> 9;                            // 0..3
  const int n = g & 1;

  const size_t fbase = (size_t)g * 32 * 256;
  const int tile0 = sblk * TILES_PER;

  // Q fragment (B-operand): col q = w*16 + l15, k(d) = quad*8..+8
  half8 qhi = Gqhi[fbase + (size_t)qt * 256 + w * 64 + lane];
  half8 qlo = Gqlo[fbase + (size_t)qt * 256 + w * 64 + lane];

  // ones A-frag (row 0 = 1): l accumulator row
  half8 onesA;
  #pragma unroll
  for (int i = 0; i < 8; ++i) onesA[i] = (l15 == 0) ? (_Float16)1.0f : (_Float16)0.0f;

  float m_q = -1.0e30f;
  f32x4 O0, O1, Ol;
  O0 = (f32x4){0.f, 0.f, 0.f, 0.f};
  O1 = (f32x4){0.f, 0.f, 0.f, 0.f};
  Ol = (f32x4){0.f, 0.f, 0.f, 0.f};

  const half8* kh  = Gkhi + fbase + (size_t)tile0 * 256 + lane;
  const half8* kl  = Gklo + fbase + (size_t)tile0 * 256 + lane;
  const half8* gv  = Gv   + fbase + (size_t)tile0 * 256 + tid;
  const float* kmp = kmask + (size_t)n * TSEQ + tile0 * 64 + quad * 4;

  half8 KH[4], KL[4];
  #pragma unroll
  for (int f = 0; f < 4; ++f) { KH[f] = kh[f * 64]; KL[f] = kl[f * 64]; }
  Vf[0][tid] = gv[0];

  #pragma unroll
  for (int tt = 0; tt < TILES_PER; ++tt) {
    half8 KHn[4], KLn[4], vnext;
    if (tt < TILES_PER - 1) {
      #pragma unroll
      for (int f = 0; f < 4; ++f) { KHn[f] = kh[256 + f * 64]; KLn[f] = kl[256 + f * 64]; }
      vnext = gv[256];
    }
    // kmask for this lane's 16 keys (4 float4 broadcasts, L1-served)
    float4 km[4];
    #pragma unroll
    for (int f = 0; f < 4; ++f) km[f] = *(const float4*)(kmp + tt * 64 + f * 16);

    __syncthreads();     // Vf[tt&1] writes visible; all reads of Vf[(tt+1)&1] done
    if (tt < TILES_PER - 1)
      Vf[(tt + 1) & 1][tid] = vnext;

    // S^T = K Q^T (split-fp16): rows = keys f*16+quad*4+r, col = q = l15
    f32x4 S[4];
    #pragma unroll
    for (int f = 0; f < 4; ++f) {
      f32x4 a = (f32x4){0.f, 0.f, 0.f, 0.f};
      a = mfma16(KL[f], qhi, a);
      a = mfma16(KH[f], qlo, a);
      a = mfma16(KH[f], qhi, a);
      S[f] = a;
    }

    // per-q max (max pollution by masked keys is harmless: O and l rescale
    // identically, the O/l ratio is invariant)
    float t0 = fmaxf(fmaxf(S[0][0], S[0][1]), fmaxf(S[0][2], S[0][3]));
    float t1 = fmaxf(fmaxf(S[1][0], S[1][1]), fmaxf(S[1][2], S[1][3]));
    float t2 = fmaxf(fmaxf(S[2][0], S[2][1]), fmaxf(S[2][2], S[2][3]));
    float t3 = fmaxf(fmaxf(S[3][0], S[3][1]), fmaxf(S[3][2], S[3][3]));
    float mx = fmaxf(fmaxf(t0, t1), fmaxf(t2, t3));
    mx = fmaxf(mx, __shfl_xor(mx, 16));
    mx = fmaxf(mx, __shfl_xor(mx, 32));

    float mnew = fmaxf(m_q, mx);
    float alpha = exp2fast(m_q - mnew);
    m_q = mnew;

    // P = kmask * exp2(S - m), pack pairs along keys -> Pbuf[q][key]
    #pragma unroll
    for (int f = 0; f < 4; ++f) {
      float p0 = exp2fast(S[f][0] - m_q) * km[f].x;
      float p1 = exp2fast(S[f][1] - m_q) * km[f].y;
      float p2 = exp2fast(S[f][2] - m_q) * km[f].z;
      float p3 = exp2fast(S[f][3] - m_q) * km[f].w;
      *(half2t*)&Pbuf[w][l15][f * 16 + quad * 4]     = pkrtz(p0, p1);
      *(half2t*)&Pbuf[w][l15][f * 16 + quad * 4 + 2] = pkrtz(p2, p3);
    }
    #pragma unroll
    for (int r = 0; r < 4; ++r) { O0[r] *= alpha; O1[r] *= alpha; }
    Ol[0] *= alpha;
    // in-wave LDS RAW: drain DS queue before reading P as B-fragments
    asm volatile("s_waitcnt lgkmcnt(0)" ::: "memory");

    const half8* vbuf = (const half8*)Vf[tt & 1];
    #pragma unroll
    for (int c = 0; c < 2; ++c) {
      half8 pb = *(const half8*)&Pbuf[w][l15][c * 32 + quad * 8];
      O0 = mfma16(vbuf[(c * 2 + 0) * 64 + lane], pb, O0);
      O1 = mfma16(vbuf[(c * 2 + 1) * 64 + lane], pb, O1);
      Ol = mfma16(onesA, pb, Ol);
    }

    #pragma unroll
    for (int f = 0; f < 4; ++f) { KH[f] = KHn[f]; KL[f] = KLn[f]; }
    kh += 256; kl += 256; gv += 256;
  }

  // epilogue: f16 partials (d = quad*4..+4 and +16), m/l from quad 0
  {
    int q = qt * 64 + w * 16 + l15;
    size_t idx = ((size_t)(sblk * 16 + g) * TSEQ + q) * DHEAD;
    half4t o0 = {(_Float16)O0[0], (_Float16)O0[1], (_Float16)O0[2], (_Float16)O0[3]};
    half4t o1 = {(_Float16)O1[0], (_Float16)O1[1], (_Float16)O1[2], (_Float16)O1[3]};
    *(half4t*)&Opf[idx + quad * 4]      = o0;
    *(half4t*)&Opf[idx + 16 + quad * 4] = o1;
    if (quad == 0) {
      Mp[(size_t)(sblk * 16 + g) * TSEQ + q] = m_q;
      Lp[(size_t)(sblk * 16 + g) * TSEQ + q] = Ol[0];
    }
  }
}

// ---------------- fused 4-way combine + layernorm + qmask + weight ----------------
__global__ __launch_bounds__(256) void ln_kernel(
    const _Float16* __restrict__ Opf, const float* __restrict__ Mp, const float* __restrict__ Lp,
    const float* __restrict__ gamma, const float* __restrict__ beta,
    const float* __restrict__ Qraw,
    float* __restrict__ out, float* __restrict__ wout) {
  const int wid = threadIdx.x >> 6, lane = threadIdx.x & 63;
  const int row = blockIdx.x * 4 + wid;
  const int n = row >> 11, q = row & (TSEQ - 1);
  const int hh = lane >> 3;
  const int hn = hh * NB + n;
  const int dbase = (lane & 7) * 4;

  // qmask computed in-kernel from raw Q row
  float4 qv = *(const float4*)(Qraw + (size_t)row * H_DIM + lane * 4);
  float qs = fabsf(qv.x) + fabsf(qv.y) + fabsf(qv.z) + fabsf(qv.w);
  #pragma unroll
  for (int off = 32; off > 0; off >>= 1) qs += __shfl_xor(qs, off);
  float qm = (qs != 0.0f) ? 1.0f : 0.0f;

  float m[SPLIT], l[SPLIT];
  half4t P[SPLIT];
  #pragma unroll
  for (int i = 0; i < SPLIT; ++i) {
    size_t si = (size_t)(i * 16 + hn) * TSEQ + q;
    P[i] = *(const half4t*)&Opf[si * DHEAD + dbase];
    m[i] = Mp[si];
    l[i] = Lp[si];
  }
  float mm = fmaxf(fmaxf(m[0], m[1]), fmaxf(m[2], m[3]));
  float denom = 0.f;
  float a[SPLIT];
  #pragma unroll
  for (int i = 0; i < SPLIT; ++i) { a[i] = exp2fast(m[i] - mm); denom += l[i] * a[i]; }
  float inv = qm / denom;

  float4 x = make_float4(0.f, 0.f, 0.f, 0.f);
  #pragma unroll
  for (int i = 0; i < SPLIT; ++i) {
    x.x += (float)P[i][0] * a[i]; x.y += (float)P[i][1] * a[i];
    x.z += (float)P[i][2] * a[i]; x.w += (float)P[i][3] * a[i];
  }
  x.x *= inv; x.y *= inv; x.z *= inv; x.w *= inv;

  float s = x.x + x.y + x.z + x.w;
  #pragma unroll
  for (int off = 32; off > 0; off >>= 1) s += __shfl_xor(s, off);
  float mu = s * (1.0f / H_DIM);
  float dx0 = x.x - mu, dx1 = x.y - mu, dx2 = x.z - mu, dx3 = x.w - mu;
  float sq = dx0 * dx0 + dx1 * dx1 + dx2 * dx2 + dx3 * dx3;
  #pragma unroll
  for (int off = 32; off > 0; off >>= 1) sq += __shfl_xor(sq, off);
  float rstd = rsqrtf(sq * (1.0f / H_DIM) + LN_EPS);
  float4 g = *(const float4*)(gamma + lane * 4);
  float4 bb = *(const float4*)(beta + lane * 4);
  float4 y;
  y.x = dx0 * rstd * g.x + bb.x;
  y.y = dx1 * rstd * g.y + bb.y;
  y.z = dx2 * rstd * g.z + bb.z;
  y.w = dx3 * rstd * g.w + bb.w;
  *(float4*)(out + (size_t)row * H_DIM + lane * 4) = y;
  if (lane == 0) wout[row] = qm * (1.0f / TSEQ);
}

extern "C" void kernel_launch(void* const* d_in, const int* in_sizes, int n_in,
                              void* d_out, int out_size, void* d_ws, size_t ws_size,
                              hipStream_t stream) {
  const float* Q  = (const float*)d_in[0];
  const float* K  = (const float*)d_in[1];
  const float* V  = (const float*)d_in[2];
  const float* Wq = (const float*)d_in[3];
  const float* bq = (const float*)d_in[4];
  const float* Wk = (const float*)d_in[5];
  const float* bk = (const float*)d_in[6];
  const float* Wv = (const float*)d_in[7];
  const float* bv = (const float*)d_in[8];
  const float* gamma = (const float*)d_in[9];
  const float* beta  = (const float*)d_in[10];

  char* ws = (char*)d_ws;
  const size_t NFRAG = (size_t)16 * 32 * 256;            // frags per array
  _Float16* Opf = (_Float16*)ws;                          // [SPLIT][16][TSEQ][32] f16 = 8 MB
  half8* Gqhi = (half8*)(ws + (size_t)SPLIT * 16 * TSEQ * DHEAD * 2);
  half8* Gqlo = Gqhi + NFRAG;
  half8* Gkhi = Gqlo + NFRAG;
  half8* Gklo = Gkhi + NFRAG;
  half8* Gv   = Gklo + NFRAG;
  float* Mp = (float*)(Gv + NFRAG);                       // [SPLIT][16][TSEQ]
  float* Lp = Mp + SPLIT * 16 * TSEQ;
  float* kmask = Lp + SPLIT * 16 * TSEQ;                  // [NB][TSEQ]
  half8* WpkHi = (half8*)(kmask + NB * TSEQ);
  half8* WpkLo = WpkHi + 24576;

  float* out  = (float*)d_out;
  float* wout = out + (size_t)NB * TSEQ * H_DIM;

  hipLaunchKernelGGL(prepack_kernel, dim3(96 + NB * TSEQ / 4), dim3(256), 0, stream,
                     Wq, Wk, Wv, K, WpkHi, WpkLo, kmask);
  hipLaunchKernelGGL(proj_kernel, dim3(H_DIM / 64, NB * TSEQ / 64, 3), dim3(256), 0, stream,
                     Q, K, V, bq, bk, bv, WpkHi, WpkLo,
                     Gqhi, Gqlo, Gkhi, Gklo, Gv);
  hipLaunchKernelGGL(attn_kernel, dim3(16 * 32 * SPLIT), dim3(256), 0, stream,
                     Gqhi, Gqlo, Gkhi, Gklo, Gv, kmask, Opf, Mp, Lp);
  hipLaunchKernelGGL(ln_kernel, dim3(NB * TSEQ / 4), dim3(256), 0, stream,
                     Opf, Mp, Lp, gamma, beta, Q, out, wout);
}